// Round 20
// baseline (151.863 us; speedup 1.0000x reference)
//
#include <hip/hip_runtime.h>
#include <hip/hip_bf16.h>
#include <stdint.h>

// ---- problem dims (fixed) ----
#define B_   8
#define S_   2048
#define D_   768
#define BS_  16384   // B_*S_
#define F_   1536    // 2*D_

typedef __attribute__((ext_vector_type(8))) short short8;    // 8 bf16 MFMA frag
typedef __attribute__((ext_vector_type(4))) float f32x4;     // 16x16 acc frag
typedef __attribute__((ext_vector_type(4))) float float4v;
typedef __attribute__((ext_vector_type(4))) unsigned short ushort4v;

__device__ __forceinline__ unsigned short f2bf(float f) {
  union { float f; unsigned u; } v; v.f = f;
  unsigned r = v.u + 0x7FFFu + ((v.u >> 16) & 1u);   // RNE
  return (unsigned short)(r >> 16);
}
__device__ __forceinline__ float bf2f(unsigned short h) {
  union { unsigned u; float f; } v; v.u = ((unsigned)h) << 16;
  return v.f;
}
__device__ __forceinline__ unsigned cvtpk_bf16(float lo, float hi) {
  unsigned r; asm("v_cvt_pk_bf16_f32 %0, %1, %2" : "=v"(r) : "v"(lo), "v"(hi)); return r;
}

#define GLOAD16(gp, lp) \
  __builtin_amdgcn_global_load_lds((const __attribute__((address_space(1))) void*)(gp), \
                                   (__attribute__((address_space(3))) void*)(lp), 16, 0, 0)

// ---------------- fused cast kernel: two f32->bf16 streams, 8 elem/thread each --------
__global__ __launch_bounds__(256) void k_cast8x2(const float* __restrict__ s1,
                                                 const float* __restrict__ s2,
                                                 unsigned short* __restrict__ d1,
                                                 unsigned short* __restrict__ d2, int n) {
  int i = (blockIdx.x * 256 + threadIdx.x) * 8;
  if (i >= n) return;
  {
    float4v a = *(const float4v*)(s1 + i);
    float4v b2 = *(const float4v*)(s1 + i + 4);
    union { short8 s; unsigned u[4]; } o;
    o.u[0] = cvtpk_bf16(a[0], a[1]); o.u[1] = cvtpk_bf16(a[2], a[3]);
    o.u[2] = cvtpk_bf16(b2[0], b2[1]); o.u[3] = cvtpk_bf16(b2[2], b2[3]);
    *(short8*)(d1 + i) = o.s;
  }
  {
    float4v a = *(const float4v*)(s2 + i);
    float4v b2 = *(const float4v*)(s2 + i + 4);
    union { short8 s; unsigned u[4]; } o;
    o.u[0] = cvtpk_bf16(a[0], a[1]); o.u[1] = cvtpk_bf16(a[2], a[3]);
    o.u[2] = cvtpk_bf16(b2[0], b2[1]); o.u[3] = cvtpk_bf16(b2[2], b2[3]);
    *(short8*)(d2 + i) = o.s;
  }
}

// Both weight transposes in one launch. y<24: Wg[768][768]; y>=24: Wf[1536][768].
__global__ __launch_bounds__(256) void k_transpose2(const float* __restrict__ Wg,
                                                    const float* __restrict__ Wf,
                                                    unsigned short* __restrict__ WgT,
                                                    unsigned short* __restrict__ WfT) {
  __shared__ float tile[32][33];
  int yy = blockIdx.y;
  const float* src; unsigned short* dst; int R, by;
  if (yy < 24) { src = Wg; dst = WgT; R = D_;  by = yy * 32; }
  else         { src = Wf; dst = WfT; R = F_;  by = (yy - 24) * 32; }
  int bx = blockIdx.x * 32;   // C index (0..768)
  int tx = threadIdx.x & 31, ty = threadIdx.x >> 5;   // 32 x 8
#pragma unroll
  for (int k = 0; k < 32; k += 8)
    tile[ty + k][tx] = src[(size_t)(by + ty + k) * D_ + bx + tx];
  __syncthreads();
#pragma unroll
  for (int k = 0; k < 32; k += 8)
    dst[(size_t)(bx + ty + k) * R + by + tx] = f2bf(tile[tx][ty + k]);
}

// ---------------- GEMM0: 128x192 tile, BK=64 (measured best for the f32-out GEMM) -----
__global__ __launch_bounds__(256, 2) void k_gemm0(const unsigned short* __restrict__ A,
                                                  const unsigned short* __restrict__ A2,
                                                  const unsigned short* __restrict__ BT,
                                                  int K, int Ksplit,
                                                  float* __restrict__ outF,
                                                  const float* __restrict__ bias) {
  __shared__ unsigned short smem[40960];   // 80KB: buf h at h*20480 (A 8192 + B 12288)
  int lin = blockIdx.x;                    // 512 blocks, bijective XCD chunk
  int nl  = (lin & 7) * 64 + (lin >> 3);
  int mBase = (nl >> 2) * 128;
  int nBase = (nl & 3) * 192;
  int t = threadIdx.x;
  int w = t >> 6, l = t & 63;
  int lm = l & 15, lg = l >> 4;
  int wm = w >> 1, wn = w & 1;
  f32x4 acc[4][6] = {};
  const int KT = K >> 6;

  auto stage = [&](int kt, int half) {
    unsigned short* Ab = smem + half * 20480;
    unsigned short* Bb = Ab + 8192;
    const unsigned short* As = (kt < Ksplit) ? A : A2;
    int ka = (kt < Ksplit) ? kt : kt - Ksplit;
#pragma unroll
    for (int i = 0; i < 4; ++i) {
      int g = i * 256 + t;
      int r = g >> 3;
      int c = (g & 7) ^ (r & 7);
      GLOAD16(As + (size_t)(mBase + r) * 768 + ka + c * 8, (char*)Ab + i * 4096 + w * 1024);
    }
#pragma unroll
    for (int i = 0; i < 6; ++i) {
      int g = i * 256 + t;
      int r = g >> 3;
      int c = (g & 7) ^ (r & 7);
      GLOAD16(BT + (size_t)(nBase + r) * K + kt + c * 8, (char*)Bb + i * 4096 + w * 1024);
    }
  };

  stage(0, 0);
  for (int kt = 0; kt < KT; ++kt) {
    int half = kt & 1;
    if (kt + 1 < KT) {
      stage((kt + 1) * 64, half ^ 1);
      asm volatile("s_waitcnt vmcnt(10)" ::: "memory");
    } else {
      asm volatile("s_waitcnt vmcnt(0)" ::: "memory");
    }
    __builtin_amdgcn_s_barrier();
    __builtin_amdgcn_sched_barrier(0);
    unsigned short* Ab = smem + half * 20480;
    unsigned short* Bb = Ab + 8192;
    __builtin_amdgcn_s_setprio(1);
#pragma unroll
    for (int ks = 0; ks < 2; ++ks) {
      short8 af[4], bfr[6];
#pragma unroll
      for (int mi = 0; mi < 4; ++mi) {
        int r = wm * 64 + mi * 16 + lm;
        int c = (ks * 4 + lg) ^ (r & 7);
        af[mi] = *(const short8*)(Ab + r * 64 + c * 8);
      }
#pragma unroll
      for (int ni = 0; ni < 6; ++ni) {
        int r = wn * 96 + ni * 16 + lm;
        int c = (ks * 4 + lg) ^ (r & 7);
        bfr[ni] = *(const short8*)(Bb + r * 64 + c * 8);
      }
#pragma unroll
      for (int mi = 0; mi < 4; ++mi)
#pragma unroll
        for (int ni = 0; ni < 6; ++ni)
          acc[mi][ni] = __builtin_amdgcn_mfma_f32_16x16x32_bf16(af[mi], bfr[ni], acc[mi][ni], 0, 0, 0);
    }
    __builtin_amdgcn_s_setprio(0);
    __builtin_amdgcn_sched_barrier(0);
    __builtin_amdgcn_s_barrier();
  }

#pragma unroll
  for (int mi = 0; mi < 4; ++mi) {
    int m = mBase + wm * 64 + mi * 16 + lg * 4;
#pragma unroll
    for (int ni = 0; ni < 6; ++ni) {
      int n = nBase + wn * 96 + ni * 16 + lm;
      float bv = bias[n];
#pragma unroll
      for (int r = 0; r < 4; ++r)
        outF[(size_t)(m + r) * 768 + n] = acc[mi][ni][r] + bv;
    }
  }
}

// ---------------- GEMM1 (round-12 proven): 128x128, BK=64, bf16 out + fused alphas ----
__global__ __launch_bounds__(256, 2) void k_gemm1(const unsigned short* __restrict__ A,
                                                  const unsigned short* __restrict__ BT,
                                                  int K,
                                                  unsigned short* __restrict__ outT,
                                                  const float* __restrict__ aS,
                                                  const float* __restrict__ aD,
                                                  float* __restrict__ asO,
                                                  float* __restrict__ adO) {
  __shared__ unsigned short smem[32768];   // A0 B0 A1 B1, each [128][64]
  int lin = blockIdx.x;                    // 768 blocks, bijective XCD chunk
  int nl  = (lin & 7) * 96 + (lin >> 3);
  int mBase = (nl / 6) * 128;
  int nBase = (nl % 6) * 128;
  int t = threadIdx.x;
  int w = t >> 6, l = t & 63;
  int lm = l & 15, lg = l >> 4;
  int wm = w >> 1, wn = w & 1;
  f32x4 acc[4][4] = {};
  const int KT = K >> 6;

  auto stage = [&](int kt, int half) {
    unsigned short* Ab = smem + half * 16384;
    unsigned short* Bb = Ab + 8192;
#pragma unroll
    for (int i = 0; i < 4; ++i) {
      int g = i * 256 + t;
      int r = g >> 3;
      int c = (g & 7) ^ (r & 7);
      GLOAD16(A  + (size_t)(mBase + r) * 768 + kt + c * 8, (char*)Ab + i * 4096 + w * 1024);
      GLOAD16(BT + (size_t)(nBase + r) * K + kt + c * 8, (char*)Bb + i * 4096 + w * 1024);
    }
  };

  stage(0, 0);
  for (int kt = 0; kt < KT; ++kt) {
    int half = kt & 1;
    if (kt + 1 < KT) {
      stage((kt + 1) * 64, half ^ 1);
      asm volatile("s_waitcnt vmcnt(8)" ::: "memory");
    } else {
      asm volatile("s_waitcnt vmcnt(0)" ::: "memory");
    }
    __builtin_amdgcn_s_barrier();
    __builtin_amdgcn_sched_barrier(0);
    unsigned short* Ab = smem + half * 16384;
    unsigned short* Bb = Ab + 8192;
    __builtin_amdgcn_s_setprio(1);
#pragma unroll
    for (int ks = 0; ks < 2; ++ks) {
      short8 af[4], bfr[4];
#pragma unroll
      for (int mi = 0; mi < 4; ++mi) {
        int r = wm * 64 + mi * 16 + lm;
        int c = (ks * 4 + lg) ^ (r & 7);
        af[mi] = *(const short8*)(Ab + r * 64 + c * 8);
      }
#pragma unroll
      for (int ni = 0; ni < 4; ++ni) {
        int r = wn * 64 + ni * 16 + lm;
        int c = (ks * 4 + lg) ^ (r & 7);
        bfr[ni] = *(const short8*)(Bb + r * 64 + c * 8);
      }
#pragma unroll
      for (int mi = 0; mi < 4; ++mi)
#pragma unroll
        for (int ni = 0; ni < 4; ++ni)
          acc[mi][ni] = __builtin_amdgcn_mfma_f32_16x16x32_bf16(af[mi], bfr[ni], acc[mi][ni], 0, 0, 0);
    }
    __builtin_amdgcn_s_setprio(0);
    __builtin_amdgcn_sched_barrier(0);
    __builtin_amdgcn_s_barrier();
  }

  // stage acc as [m][n] bf16 in smem (group-XOR swizzled), then coalesced rows out
#pragma unroll
  for (int mi = 0; mi < 4; ++mi) {
#pragma unroll
    for (int ni = 0; ni < 4; ++ni) {
      int col = wn * 64 + ni * 16 + lm;
#pragma unroll
      for (int r = 0; r < 4; ++r) {
        int row = wm * 64 + mi * 16 + lg * 4 + r;
        int phys = (((col >> 3) ^ (row & 7)) << 3) | (col & 7);
        smem[row * 128 + phys] = f2bf(acc[mi][ni][r]);
      }
    }
  }
  float* aLds = (float*)(smem + 16384);
  if (t < 128) {
    aLds[t] = aS[nBase + t];
    aLds[128 + t] = aD[nBase + t];
  }
  __syncthreads();
#pragma unroll
  for (int it = 0; it < 8; ++it) {
    int row = it * 16 + (t >> 4);
    int gg = t & 15;
    short8 v = *(const short8*)(&smem[row * 128 + ((gg ^ (row & 7)) << 3)]);
    *(short8*)(outT + (size_t)(mBase + row) * 768 + nBase + gg * 8) = v;
  }
  // fused alpha partial dots: thread pair (row, half) covers 64 cols each
  {
    int row = t >> 1, halfc = t & 1;
    float accs = 0.f, accd = 0.f;
#pragma unroll
    for (int gg = 0; gg < 8; ++gg) {
      int cq = halfc * 8 + gg;
      short8 v = *(const short8*)(&smem[row * 128 + ((cq ^ (row & 7)) << 3)]);
#pragma unroll
      for (int e = 0; e < 8; ++e) {
        float x = bf2f((unsigned short)v[e]);
        accs = fmaf(aLds[cq * 8 + e], x, accs);
        accd = fmaf(aLds[128 + cq * 8 + e], x, accd);
      }
    }
    accs += __shfl_xor(accs, 1);
    accd += __shfl_xor(accd, 1);
    if (halfc == 0) {
      atomicAdd(asO + mBase + row, accs);
      atomicAdd(adO + mBase + row, accd);
    }
  }
}

// ---------------- rank-by-count: grid (64, 8), 32 j x 8 k-parts per block ----------
__global__ __launch_bounds__(256) void k_rank(const float* __restrict__ as,
                                              float* __restrict__ ssorted, int* __restrict__ sidx,
                                              float* __restrict__ es1g, float* __restrict__ es2g,
                                              float* __restrict__ msg) {
  __shared__ float sjl[S_];
  __shared__ float red[256];
  __shared__ int rk[32][9];          // 9-pad: bank-conflict-free column reads
  int b = blockIdx.y, t = threadIdx.x;
  float lmx = -1e30f;
#pragma unroll
  for (int q = 0; q < 2; ++q) {
    int p = (t + q * 256) * 4;
    float4v v = *(const float4v*)(as + b * S_ + p);
    *(float4v*)(sjl + p) = v;
    lmx = fmaxf(lmx, fmaxf(fmaxf(v[0], v[1]), fmaxf(v[2], v[3])));
  }
  red[t] = lmx;
  __syncthreads();
  for (int st = 128; st > 0; st >>= 1) {
    if (t < st) red[t] = fmaxf(red[t], red[t + st]);
    __syncthreads();
  }
  float Ms = red[0];
  int jl = t & 31, part = t >> 5;
  int j = blockIdx.x * 32 + jl;
  float sj = sjl[j];
  int r0 = 0, r1 = 0, r2 = 0, r3 = 0;
  int kbase = part * 256;
#pragma unroll 8
  for (int kq = 0; kq < 64; ++kq) {
    int k = kbase + kq * 4;
    float4v sk = *(const float4v*)(sjl + k);       // wave-broadcast per 32 lanes
    r0 += (sk[0] < sj) | ((sk[0] == sj) & (k < j));
    r1 += (sk[1] < sj) | ((sk[1] == sj) & (k + 1 < j));
    r2 += (sk[2] < sj) | ((sk[2] == sj) & (k + 2 < j));
    r3 += (sk[3] < sj) | ((sk[3] == sj) & (k + 3 < j));
  }
  rk[jl][part] = r0 + r1 + r2 + r3;
  __syncthreads();
  if (t < 32) {
    int rank = rk[t][0] + rk[t][1] + rk[t][2] + rk[t][3]
             + rk[t][4] + rk[t][5] + rk[t][6] + rk[t][7];
    int jj = blockIdx.x * 32 + t;
    float sv = sjl[jj];
    ssorted[b * S_ + rank] = sv;
    sidx[b * S_ + rank] = jj;
    es1g[b * S_ + rank] = __expf(sv - Ms);
    es2g[b * S_ + rank] = __expf(0.2f * (sv - Ms));
    if (blockIdx.x == 0 && t == 0) msg[b] = Ms;
  }
}

// ---------------- chunk scalar scans: sufug (suffix) / prevg (exclusive prefix) -------
__global__ __launch_bounds__(256) void k_pscan(const float* __restrict__ es1g,
                                               const float* __restrict__ es2g,
                                               float* __restrict__ sufug,
                                               float* __restrict__ prevg) {
  __shared__ float su[256], pv[256];
  int b = blockIdx.x, t = threadIdx.x;
  float a1 = 0.f, a2 = 0.f;
#pragma unroll
  for (int r = 0; r < 8; ++r) {
    a1 += es1g[b * S_ + t * 8 + r];
    a2 += es2g[b * S_ + t * 8 + r];
  }
  su[t] = a1; pv[t] = a2;
  __syncthreads();
  for (int off = 1; off < 256; off <<= 1) {
    float vs = (t + off < 256) ? su[t + off] : 0.f;   // suffix-inclusive
    float vp = (t >= off) ? pv[t - off] : 0.f;        // prefix-inclusive
    __syncthreads();
    su[t] += vs; pv[t] += vp;
    __syncthreads();
  }
  sufug[b * 260 + t] = su[t];
  prevg[b * 260 + t] = (t > 0) ? pv[t - 1] : 0.f;
  if (t == 0) sufug[b * 260 + 256] = 0.f;
}

// ---------------- chunk sums: SU/SV[b][c][768] (f32) over 8 sorted rows each ----------
__global__ __launch_bounds__(192) void k_chunks(const unsigned short* __restrict__ xp,
                                                const int* __restrict__ sidx,
                                                const float* __restrict__ es1g,
                                                const float* __restrict__ es2g,
                                                float* __restrict__ SU, float* __restrict__ SV) {
  __shared__ int ridx[64];
  __shared__ float w1l[64], w2l[64];
  int b = blockIdx.y, cblk = blockIdx.x;   // 32 cblks x 8 chunks
  int t = threadIdx.x;
  if (t < 64) {
    int r = cblk * 64 + t;
    ridx[t] = sidx[b * S_ + r];
    w1l[t] = es1g[b * S_ + r];
    w2l[t] = es2g[b * S_ + r];
  }
  __syncthreads();
  int d0 = t * 4;
  const unsigned short* xb = xp + (size_t)b * S_ * D_;
  for (int q = 0; q < 8; ++q) {
    float a1[4] = {0.f, 0.f, 0.f, 0.f}, a2[4] = {0.f, 0.f, 0.f, 0.f};
#pragma unroll
    for (int r = 0; r < 8; ++r) {
      int j = q * 8 + r;
      ushort4v xv = *(const ushort4v*)(xb + (size_t)ridx[j] * D_ + d0);
      float w1 = w1l[j], w2 = w2l[j];
#pragma unroll
      for (int e = 0; e < 4; ++e) {
        float x = bf2f(xv[e]);
        a1[e] = fmaf(w1, x, a1[e]);
        a2[e] = fmaf(w2, x, a2[e]);
      }
    }
    int c = cblk * 8 + q;
    float4v o1, o2;
    o1[0] = a1[0]; o1[1] = a1[1]; o1[2] = a1[2]; o1[3] = a1[3];
    o2[0] = a2[0]; o2[1] = a2[1]; o2[2] = a2[2]; o2[3] = a2[3];
    *(float4v*)(SU + ((size_t)b * 256 + c) * D_ + d0) = o1;
    *(float4v*)(SV + ((size_t)b * 256 + c) * D_ + d0) = o2;
  }
}

// ---------------- scans over chunks: f32 in, bf16 out ----------------
__global__ __launch_bounds__(256) void k_scan(const float* __restrict__ SU,
                                              const float* __restrict__ SV,
                                              unsigned short* __restrict__ SUb,
                                              unsigned short* __restrict__ SVb) {
  __shared__ float sums[8][33];
  int b = blockIdx.y;
  int dl = threadIdx.x & 31, p = threadIdx.x >> 5;   // 32 d-cols x 8 c-parts
  int d = blockIdx.x * 32 + dl;
  const float* u = SU + (size_t)b * 256 * D_ + d;
  const float* v = SV + (size_t)b * 256 * D_ + d;
  unsigned short* ub = SUb + (size_t)b * 257 * D_ + d;
  unsigned short* vb = SVb + (size_t)b * 256 * D_ + d;
  int c0 = p * 32;
  float cu[32], cv[32];
  float su_ = 0.f, sv_ = 0.f;
#pragma unroll
  for (int q = 0; q < 32; ++q) {
    cu[q] = u[(size_t)(c0 + q) * D_];
    cv[q] = v[(size_t)(c0 + q) * D_];
    su_ += cu[q]; sv_ += cv[q];
  }
  sums[p][dl] = su_;
  __syncthreads();
  float offU = 0.f;
#pragma unroll
  for (int q = 0; q < 8; ++q) if (q > p) offU += sums[q][dl];
  __syncthreads();
  sums[p][dl] = sv_;
  __syncthreads();
  float offV = 0.f;
#pragma unroll
  for (int q = 0; q < 8; ++q) if (q < p) offV += sums[q][dl];
  float run = offU;
#pragma unroll
  for (int q = 31; q >= 0; --q) { run += cu[q]; ub[(size_t)(c0 + q) * D_] = f2bf(run); }
  float pr = offV;
#pragma unroll
  for (int q = 0; q < 32; ++q) { vb[(size_t)(c0 + q) * D_] = f2bf(pr); pr += cv[q]; }
  if (p == 0) ub[(size_t)256 * D_] = 0;
}

// ---------------- output v6: 4-i tiles, 4096 blocks, no LDS stage, direct search ------
// Wave w owns i = i0+w (fully independent after tiny setup); lane owns dim chunks
// {lane*4, +256, +512} -> coalesced ushort4 loads throughout.
__global__ __launch_bounds__(256) void k_out(const unsigned short* __restrict__ xp,
                                             const float* __restrict__ ad,
                                             const float* __restrict__ ssorted,
                                             const int* __restrict__ sidx,
                                             const float* __restrict__ es1g,
                                             const float* __restrict__ es2g,
                                             const float* __restrict__ sufug,
                                             const float* __restrict__ prevg,
                                             const float* __restrict__ msg,
                                             const unsigned short* __restrict__ SUb,
                                             const unsigned short* __restrict__ SVb,
                                             const float* __restrict__ b_gat,
                                             unsigned short* __restrict__ gout) {
  __shared__ float G1[4], G2[4], WL[4][8];
  __shared__ int CI[4], RI[4][8];
  int bid = blockIdx.x;                 // 4096 blocks; bid&7 = batch (XCD affinity)
  int b = bid & 7, itile = bid >> 3;    // itile 0..511
  int i0 = itile * 4;
  int t = threadIdx.x;
  if (t < 4) {
    int i = i0 + t;
    float di = ad[b * S_ + i];
    float thr = -di;
    const float* sk = ssorted + b * S_;   // 8KB/batch, L2-hot; direct binary search
    int lo = 0, hi = 2048;
#pragma unroll
    for (int st = 0; st < 11; ++st) {
      int mid = (lo + hi) >> 1;
      if (sk[mid] <= thr) lo = mid + 1; else hi = mid;
    }
    int c = lo >> 3; if (c > 255) c = 255;
    float t1 = di + msg[b];
    float mst = fmaxf(t1, 0.2f * t1);
    float g1 = __expf(t1 - mst), g2 = __expf(0.2f * t1 - mst);
    float den = g1 * sufug[b * 260 + c + 1] + g2 * prevg[b * 260 + c];
    float wr[8]; int rid[8];
#pragma unroll
    for (int r = 0; r < 8; ++r) {
      int row = c * 8 + r;
      bool neg = (sk[row] <= thr);
      float wv = neg ? g2 * es2g[b * S_ + row] : g1 * es1g[b * S_ + row];
      den += wv;
      wr[r] = wv;
      rid[r] = sidx[b * S_ + row];
    }
    float inv = 1.f / den;
    G1[t] = g1 * inv; G2[t] = g2 * inv; CI[t] = c;
#pragma unroll
    for (int r = 0; r < 8; ++r) { WL[t][r] = wr[r] * inv; RI[t][r] = rid[r]; }
  }
  __syncthreads();
  int w = t >> 6, lane = t & 63;
  int dbase = lane * 4;
  float4v bgv[3];
#pragma unroll
  for (int q = 0; q < 3; ++q) bgv[q] = *(const float4v*)(b_gat + dbase + q * 256);
  const unsigned short* xb = xp + (size_t)b * S_ * D_;
  const unsigned short* SUbb = SUb + (size_t)b * 257 * D_;
  const unsigned short* SVbb = SVb + (size_t)b * 256 * D_;
  {
    int ii = w;                          // one i per wave, fully independent
    int c = CI[ii];
    float g1 = G1[ii], g2 = G2[ii];
    size_t roff = ((size_t)(b * S_ + i0 + ii)) * D_;
    float4v o[3];
#pragma unroll
    for (int q = 0; q < 3; ++q) {
      int d = dbase + q * 256;
      ushort4v uu = *(const ushort4v*)(SUbb + (size_t)(c + 1) * D_ + d);
      ushort4v vv = *(const ushort4v*)(SVbb + (size_t)c * D_ + d);
#pragma unroll
      for (int e = 0; e < 4; ++e) o[q][e] = fmaf(g1, bf2f(uu[e]), g2 * bf2f(vv[e]));
    }
#pragma unroll
    for (int r = 0; r < 8; ++r) {
      float wv = WL[ii][r];
      const unsigned short* xr = xb + (size_t)RI[ii][r] * D_;
#pragma unroll
      for (int q = 0; q < 3; ++q) {
        int d = dbase + q * 256;
        ushort4v xv = *(const ushort4v*)(xr + d);
#pragma unroll
        for (int e = 0; e < 4; ++e) o[q][e] = fmaf(wv, bf2f(xv[e]), o[q][e]);
      }
    }
#pragma unroll
    for (int q = 0; q < 3; ++q) {
      int d = dbase + q * 256;
      ushort4v og;
      og[0] = f2bf(o[q][0] + bgv[q][0]); og[1] = f2bf(o[q][1] + bgv[q][1]);
      og[2] = f2bf(o[q][2] + bgv[q][2]); og[3] = f2bf(o[q][3] + bgv[q][3]);
      *(ushort4v*)(gout + roff + d) = og;
    }
  }
}

// ---------------- launch ----------------
extern "C" void kernel_launch(void* const* d_in, const int* in_sizes, int n_in,
                              void* d_out, int out_size, void* d_ws, size_t ws_size,
                              hipStream_t stream) {
  const float* hs   = (const float*)d_in[0];
  const float* to   = (const float*)d_in[1];
  const float* Wg   = (const float*)d_in[2];
  const float* asrc = (const float*)d_in[3];
  const float* adst = (const float*)d_in[4];
  const float* bg   = (const float*)d_in[5];
  const float* Wf   = (const float*)d_in[6];
  const float* bfu  = (const float*)d_in[7];
  float* out = (float*)d_out;

  char* ws = (char*)d_ws;
  size_t off = 0;
  auto alloc = [&](size_t bytes) {
    char* p = ws + off;
    off += (bytes + 255) & ~(size_t)255;
    return p;
  };
  unsigned short* hs_bf = (unsigned short*)alloc((size_t)BS_ * D_ * 2);  // reused as gout
  unsigned short* to_bf = (unsigned short*)alloc((size_t)BS_ * D_ * 2);
  unsigned short* xp    = (unsigned short*)alloc((size_t)BS_ * D_ * 2);
  unsigned short* WgT   = (unsigned short*)alloc((size_t)D_ * D_ * 2);
  unsigned short* WfT   = (unsigned short*)alloc((size_t)D_ * F_ * 2);
  float* as   = (float*)alloc((size_t)BS_ * 4);
  float* ad   = (float*)alloc((size_t)BS_ * 4);
  float* ssorted = (float*)alloc((size_t)BS_ * 4);
  int*   sidx    = (int*)alloc((size_t)BS_ * 4);
  float* es1g = (float*)alloc((size_t)BS_ * 4);
  float* es2g = (float*)alloc((size_t)BS_ * 4);
  float* sufug = (float*)alloc((size_t)B_ * 260 * 4);
  float* prevg = (float*)alloc((size_t)B_ * 260 * 4);
  float* msg   = (float*)alloc(256);
  float* SU = (float*)alloc((size_t)B_ * 256 * D_ * 4);               // chunk sums (f32)
  float* SV = (float*)alloc((size_t)B_ * 256 * D_ * 4);
  unsigned short* SUb = (unsigned short*)alloc((size_t)B_ * 257 * D_ * 2);  // scanned, bf16
  unsigned short* SVb = (unsigned short*)alloc((size_t)B_ * 256 * D_ * 2);
  unsigned short* gout = hs_bf;   // hs_bf dead after gemm1

  int n = BS_ * D_;
  hipMemsetAsync(as, 0, (size_t)BS_ * 4, stream);
  hipMemsetAsync(ad, 0, (size_t)BS_ * 4, stream);
  k_cast8x2<<<n / 2048, 256, 0, stream>>>(hs, to, hs_bf, to_bf, n);
  k_transpose2<<<dim3(24, 72), 256, 0, stream>>>(Wg, Wf, WgT, WfT);
  k_gemm1<<<768, 256, 0, stream>>>(hs_bf, WgT, D_, xp, asrc, adst, as, ad);
  k_rank<<<dim3(64, B_), 256, 0, stream>>>(as, ssorted, sidx, es1g, es2g, msg);
  k_pscan<<<B_, 256, 0, stream>>>(es1g, es2g, sufug, prevg);
  k_chunks<<<dim3(32, B_), 192, 0, stream>>>(xp, sidx, es1g, es2g, SU, SV);
  k_scan<<<dim3(24, B_), 256, 0, stream>>>(SU, SV, SUb, SVb);
  k_out<<<4096, 256, 0, stream>>>(xp, ad, ssorted, sidx, es1g, es2g, sufug, prevg, msg,
                                  SUb, SVb, bg, gout);
  k_gemm0<<<512, 256, 0, stream>>>(to_bf, gout, WfT, F_, D_, out, bfu);
}

// Round 21
// 145.480 us; speedup vs baseline: 1.0439x; 1.0439x over previous
//
#include <hip/hip_runtime.h>
#include <hip/hip_bf16.h>
#include <stdint.h>

// ---- problem dims (fixed) ----
#define B_   8
#define S_   2048
#define D_   768
#define BS_  16384   // B_*S_
#define F_   1536    // 2*D_

typedef __attribute__((ext_vector_type(8))) short short8;    // 8 bf16 MFMA frag
typedef __attribute__((ext_vector_type(4))) float f32x4;     // 16x16 acc frag
typedef __attribute__((ext_vector_type(4))) float float4v;
typedef __attribute__((ext_vector_type(4))) unsigned short ushort4v;

__device__ __forceinline__ unsigned short f2bf(float f) {
  union { float f; unsigned u; } v; v.f = f;
  unsigned r = v.u + 0x7FFFu + ((v.u >> 16) & 1u);   // RNE
  return (unsigned short)(r >> 16);
}
__device__ __forceinline__ float bf2f(unsigned short h) {
  union { unsigned u; float f; } v; v.u = ((unsigned)h) << 16;
  return v.f;
}
__device__ __forceinline__ unsigned cvtpk_bf16(float lo, float hi) {
  unsigned r; asm("v_cvt_pk_bf16_f32 %0, %1, %2" : "=v"(r) : "v"(lo), "v"(hi)); return r;
}

#define GLOAD16(gp, lp) \
  __builtin_amdgcn_global_load_lds((const __attribute__((address_space(1))) void*)(gp), \
                                   (__attribute__((address_space(3))) void*)(lp), 16, 0, 0)

// ------- fused cast kernel: two f32->bf16 streams + as/ad zeroing (first 64 blocks) ----
__global__ __launch_bounds__(256) void k_cast8x2(const float* __restrict__ s1,
                                                 const float* __restrict__ s2,
                                                 unsigned short* __restrict__ d1,
                                                 unsigned short* __restrict__ d2, int n,
                                                 float* __restrict__ z1,
                                                 float* __restrict__ z2) {
  if (blockIdx.x < 64) {   // zero as/ad (64 blocks x 256 thr x 1 f32 each array)
    int zi = blockIdx.x * 256 + threadIdx.x;
    z1[zi] = 0.f;
    z2[zi] = 0.f;
  }
  int i = (blockIdx.x * 256 + threadIdx.x) * 8;
  if (i >= n) return;
  {
    float4v a = *(const float4v*)(s1 + i);
    float4v b2 = *(const float4v*)(s1 + i + 4);
    union { short8 s; unsigned u[4]; } o;
    o.u[0] = cvtpk_bf16(a[0], a[1]); o.u[1] = cvtpk_bf16(a[2], a[3]);
    o.u[2] = cvtpk_bf16(b2[0], b2[1]); o.u[3] = cvtpk_bf16(b2[2], b2[3]);
    *(short8*)(d1 + i) = o.s;
  }
  {
    float4v a = *(const float4v*)(s2 + i);
    float4v b2 = *(const float4v*)(s2 + i + 4);
    union { short8 s; unsigned u[4]; } o;
    o.u[0] = cvtpk_bf16(a[0], a[1]); o.u[1] = cvtpk_bf16(a[2], a[3]);
    o.u[2] = cvtpk_bf16(b2[0], b2[1]); o.u[3] = cvtpk_bf16(b2[2], b2[3]);
    *(short8*)(d2 + i) = o.s;
  }
}

// Wait: as/ad are 16384 f32 each; 64 blocks x 256 = 16384 -> exactly covered.

// Both weight transposes in one launch. y<24: Wg[768][768]; y>=24: Wf[1536][768].
__global__ __launch_bounds__(256) void k_transpose2(const float* __restrict__ Wg,
                                                    const float* __restrict__ Wf,
                                                    unsigned short* __restrict__ WgT,
                                                    unsigned short* __restrict__ WfT) {
  __shared__ float tile[32][33];
  int yy = blockIdx.y;
  const float* src; unsigned short* dst; int R, by;
  if (yy < 24) { src = Wg; dst = WgT; R = D_;  by = yy * 32; }
  else         { src = Wf; dst = WfT; R = F_;  by = (yy - 24) * 32; }
  int bx = blockIdx.x * 32;   // C index (0..768)
  int tx = threadIdx.x & 31, ty = threadIdx.x >> 5;   // 32 x 8
#pragma unroll
  for (int k = 0; k < 32; k += 8)
    tile[ty + k][tx] = src[(size_t)(by + ty + k) * D_ + bx + tx];
  __syncthreads();
#pragma unroll
  for (int k = 0; k < 32; k += 8)
    dst[(size_t)(bx + ty + k) * R + by + tx] = f2bf(tile[tx][ty + k]);
}

// ---------------- GEMM0: 128x192 tile, BK=64 (measured best for the f32-out GEMM) -----
__global__ __launch_bounds__(256, 2) void k_gemm0(const unsigned short* __restrict__ A,
                                                  const unsigned short* __restrict__ A2,
                                                  const unsigned short* __restrict__ BT,
                                                  int K, int Ksplit,
                                                  float* __restrict__ outF,
                                                  const float* __restrict__ bias) {
  __shared__ unsigned short smem[40960];   // 80KB: buf h at h*20480 (A 8192 + B 12288)
  int lin = blockIdx.x;                    // 512 blocks, bijective XCD chunk
  int nl  = (lin & 7) * 64 + (lin >> 3);
  int mBase = (nl >> 2) * 128;
  int nBase = (nl & 3) * 192;
  int t = threadIdx.x;
  int w = t >> 6, l = t & 63;
  int lm = l & 15, lg = l >> 4;
  int wm = w >> 1, wn = w & 1;
  f32x4 acc[4][6] = {};
  const int KT = K >> 6;

  auto stage = [&](int kt, int half) {
    unsigned short* Ab = smem + half * 20480;
    unsigned short* Bb = Ab + 8192;
    const unsigned short* As = (kt < Ksplit) ? A : A2;
    int ka = (kt < Ksplit) ? kt : kt - Ksplit;
#pragma unroll
    for (int i = 0; i < 4; ++i) {
      int g = i * 256 + t;
      int r = g >> 3;
      int c = (g & 7) ^ (r & 7);
      GLOAD16(As + (size_t)(mBase + r) * 768 + ka + c * 8, (char*)Ab + i * 4096 + w * 1024);
    }
#pragma unroll
    for (int i = 0; i < 6; ++i) {
      int g = i * 256 + t;
      int r = g >> 3;
      int c = (g & 7) ^ (r & 7);
      GLOAD16(BT + (size_t)(nBase + r) * K + kt + c * 8, (char*)Bb + i * 4096 + w * 1024);
    }
  };

  stage(0, 0);
  for (int kt = 0; kt < KT; ++kt) {
    int half = kt & 1;
    if (kt + 1 < KT) {
      stage((kt + 1) * 64, half ^ 1);
      asm volatile("s_waitcnt vmcnt(10)" ::: "memory");
    } else {
      asm volatile("s_waitcnt vmcnt(0)" ::: "memory");
    }
    __builtin_amdgcn_s_barrier();
    __builtin_amdgcn_sched_barrier(0);
    unsigned short* Ab = smem + half * 20480;
    unsigned short* Bb = Ab + 8192;
    __builtin_amdgcn_s_setprio(1);
#pragma unroll
    for (int ks = 0; ks < 2; ++ks) {
      short8 af[4], bfr[6];
#pragma unroll
      for (int mi = 0; mi < 4; ++mi) {
        int r = wm * 64 + mi * 16 + lm;
        int c = (ks * 4 + lg) ^ (r & 7);
        af[mi] = *(const short8*)(Ab + r * 64 + c * 8);
      }
#pragma unroll
      for (int ni = 0; ni < 6; ++ni) {
        int r = wn * 96 + ni * 16 + lm;
        int c = (ks * 4 + lg) ^ (r & 7);
        bfr[ni] = *(const short8*)(Bb + r * 64 + c * 8);
      }
#pragma unroll
      for (int mi = 0; mi < 4; ++mi)
#pragma unroll
        for (int ni = 0; ni < 6; ++ni)
          acc[mi][ni] = __builtin_amdgcn_mfma_f32_16x16x32_bf16(af[mi], bfr[ni], acc[mi][ni], 0, 0, 0);
    }
    __builtin_amdgcn_s_setprio(0);
    __builtin_amdgcn_sched_barrier(0);
    __builtin_amdgcn_s_barrier();
  }

#pragma unroll
  for (int mi = 0; mi < 4; ++mi) {
    int m = mBase + wm * 64 + mi * 16 + lg * 4;
#pragma unroll
    for (int ni = 0; ni < 6; ++ni) {
      int n = nBase + wn * 96 + ni * 16 + lm;
      float bv = bias[n];
#pragma unroll
      for (int r = 0; r < 4; ++r)
        outF[(size_t)(m + r) * 768 + n] = acc[mi][ni][r] + bv;
    }
  }
}

// ---------------- GEMM1 (round-12 proven): 128x128, BK=64, bf16 out + fused alphas ----
__global__ __launch_bounds__(256, 2) void k_gemm1(const unsigned short* __restrict__ A,
                                                  const unsigned short* __restrict__ BT,
                                                  int K,
                                                  unsigned short* __restrict__ outT,
                                                  const float* __restrict__ aS,
                                                  const float* __restrict__ aD,
                                                  float* __restrict__ asO,
                                                  float* __restrict__ adO) {
  __shared__ unsigned short smem[32768];   // A0 B0 A1 B1, each [128][64]
  int lin = blockIdx.x;                    // 768 blocks, bijective XCD chunk
  int nl  = (lin & 7) * 96 + (lin >> 3);
  int mBase = (nl / 6) * 128;
  int nBase = (nl % 6) * 128;
  int t = threadIdx.x;
  int w = t >> 6, l = t & 63;
  int lm = l & 15, lg = l >> 4;
  int wm = w >> 1, wn = w & 1;
  f32x4 acc[4][4] = {};
  const int KT = K >> 6;

  auto stage = [&](int kt, int half) {
    unsigned short* Ab = smem + half * 16384;
    unsigned short* Bb = Ab + 8192;
#pragma unroll
    for (int i = 0; i < 4; ++i) {
      int g = i * 256 + t;
      int r = g >> 3;
      int c = (g & 7) ^ (r & 7);
      GLOAD16(A  + (size_t)(mBase + r) * 768 + kt + c * 8, (char*)Ab + i * 4096 + w * 1024);
      GLOAD16(BT + (size_t)(nBase + r) * K + kt + c * 8, (char*)Bb + i * 4096 + w * 1024);
    }
  };

  stage(0, 0);
  for (int kt = 0; kt < KT; ++kt) {
    int half = kt & 1;
    if (kt + 1 < KT) {
      stage((kt + 1) * 64, half ^ 1);
      asm volatile("s_waitcnt vmcnt(8)" ::: "memory");
    } else {
      asm volatile("s_waitcnt vmcnt(0)" ::: "memory");
    }
    __builtin_amdgcn_s_barrier();
    __builtin_amdgcn_sched_barrier(0);
    unsigned short* Ab = smem + half * 16384;
    unsigned short* Bb = Ab + 8192;
    __builtin_amdgcn_s_setprio(1);
#pragma unroll
    for (int ks = 0; ks < 2; ++ks) {
      short8 af[4], bfr[4];
#pragma unroll
      for (int mi = 0; mi < 4; ++mi) {
        int r = wm * 64 + mi * 16 + lm;
        int c = (ks * 4 + lg) ^ (r & 7);
        af[mi] = *(const short8*)(Ab + r * 64 + c * 8);
      }
#pragma unroll
      for (int ni = 0; ni < 4; ++ni) {
        int r = wn * 64 + ni * 16 + lm;
        int c = (ks * 4 + lg) ^ (r & 7);
        bfr[ni] = *(const short8*)(Bb + r * 64 + c * 8);
      }
#pragma unroll
      for (int mi = 0; mi < 4; ++mi)
#pragma unroll
        for (int ni = 0; ni < 4; ++ni)
          acc[mi][ni] = __builtin_amdgcn_mfma_f32_16x16x32_bf16(af[mi], bfr[ni], acc[mi][ni], 0, 0, 0);
    }
    __builtin_amdgcn_s_setprio(0);
    __builtin_amdgcn_sched_barrier(0);
    __builtin_amdgcn_s_barrier();
  }

  // stage acc as [m][n] bf16 in smem (group-XOR swizzled), then coalesced rows out
#pragma unroll
  for (int mi = 0; mi < 4; ++mi) {
#pragma unroll
    for (int ni = 0; ni < 4; ++ni) {
      int col = wn * 64 + ni * 16 + lm;
#pragma unroll
      for (int r = 0; r < 4; ++r) {
        int row = wm * 64 + mi * 16 + lg * 4 + r;
        int phys = (((col >> 3) ^ (row & 7)) << 3) | (col & 7);
        smem[row * 128 + phys] = f2bf(acc[mi][ni][r]);
      }
    }
  }
  float* aLds = (float*)(smem + 16384);
  if (t < 128) {
    aLds[t] = aS[nBase + t];
    aLds[128 + t] = aD[nBase + t];
  }
  __syncthreads();
#pragma unroll
  for (int it = 0; it < 8; ++it) {
    int row = it * 16 + (t >> 4);
    int gg = t & 15;
    short8 v = *(const short8*)(&smem[row * 128 + ((gg ^ (row & 7)) << 3)]);
    *(short8*)(outT + (size_t)(mBase + row) * 768 + nBase + gg * 8) = v;
  }
  // fused alpha partial dots: thread pair (row, half) covers 64 cols each
  {
    int row = t >> 1, halfc = t & 1;
    float accs = 0.f, accd = 0.f;
#pragma unroll
    for (int gg = 0; gg < 8; ++gg) {
      int cq = halfc * 8 + gg;
      short8 v = *(const short8*)(&smem[row * 128 + ((cq ^ (row & 7)) << 3)]);
#pragma unroll
      for (int e = 0; e < 8; ++e) {
        float x = bf2f((unsigned short)v[e]);
        accs = fmaf(aLds[cq * 8 + e], x, accs);
        accd = fmaf(aLds[128 + cq * 8 + e], x, accd);
      }
    }
    accs += __shfl_xor(accs, 1);
    accd += __shfl_xor(accd, 1);
    if (halfc == 0) {
      atomicAdd(asO + mBase + row, accs);
      atomicAdd(adO + mBase + row, accd);
    }
  }
}

// ---------------- rank-by-count: grid (64, 8), 32 j x 8 k-parts per block ----------
__global__ __launch_bounds__(256) void k_rank(const float* __restrict__ as,
                                              float* __restrict__ ssorted, int* __restrict__ sidx,
                                              float* __restrict__ es1g, float* __restrict__ es2g,
                                              float* __restrict__ msg) {
  __shared__ float sjl[S_];
  __shared__ float red[256];
  __shared__ int rk[32][9];          // 9-pad: bank-conflict-free column reads
  int b = blockIdx.y, t = threadIdx.x;
  float lmx = -1e30f;
#pragma unroll
  for (int q = 0; q < 2; ++q) {
    int p = (t + q * 256) * 4;
    float4v v = *(const float4v*)(as + b * S_ + p);
    *(float4v*)(sjl + p) = v;
    lmx = fmaxf(lmx, fmaxf(fmaxf(v[0], v[1]), fmaxf(v[2], v[3])));
  }
  red[t] = lmx;
  __syncthreads();
  for (int st = 128; st > 0; st >>= 1) {
    if (t < st) red[t] = fmaxf(red[t], red[t + st]);
    __syncthreads();
  }
  float Ms = red[0];
  int jl = t & 31, part = t >> 5;
  int j = blockIdx.x * 32 + jl;
  float sj = sjl[j];
  int r0 = 0, r1 = 0, r2 = 0, r3 = 0;
  int kbase = part * 256;
#pragma unroll 8
  for (int kq = 0; kq < 64; ++kq) {
    int k = kbase + kq * 4;
    float4v sk = *(const float4v*)(sjl + k);       // wave-broadcast per 32 lanes
    r0 += (sk[0] < sj) | ((sk[0] == sj) & (k < j));
    r1 += (sk[1] < sj) | ((sk[1] == sj) & (k + 1 < j));
    r2 += (sk[2] < sj) | ((sk[2] == sj) & (k + 2 < j));
    r3 += (sk[3] < sj) | ((sk[3] == sj) & (k + 3 < j));
  }
  rk[jl][part] = r0 + r1 + r2 + r3;
  __syncthreads();
  if (t < 32) {
    int rank = rk[t][0] + rk[t][1] + rk[t][2] + rk[t][3]
             + rk[t][4] + rk[t][5] + rk[t][6] + rk[t][7];
    int jj = blockIdx.x * 32 + t;
    float sv = sjl[jj];
    ssorted[b * S_ + rank] = sv;
    sidx[b * S_ + rank] = jj;
    es1g[b * S_ + rank] = __expf(sv - Ms);
    es2g[b * S_ + rank] = __expf(0.2f * (sv - Ms));
    if (blockIdx.x == 0 && t == 0) msg[b] = Ms;
  }
}

// ---------------- chunk scalar scans: sufug (suffix) / prevg (exclusive prefix) -------
__global__ __launch_bounds__(256) void k_pscan(const float* __restrict__ es1g,
                                               const float* __restrict__ es2g,
                                               float* __restrict__ sufug,
                                               float* __restrict__ prevg) {
  __shared__ float su[256], pv[256];
  int b = blockIdx.x, t = threadIdx.x;
  float a1 = 0.f, a2 = 0.f;
#pragma unroll
  for (int r = 0; r < 8; ++r) {
    a1 += es1g[b * S_ + t * 8 + r];
    a2 += es2g[b * S_ + t * 8 + r];
  }
  su[t] = a1; pv[t] = a2;
  __syncthreads();
  for (int off = 1; off < 256; off <<= 1) {
    float vs = (t + off < 256) ? su[t + off] : 0.f;   // suffix-inclusive
    float vp = (t >= off) ? pv[t - off] : 0.f;        // prefix-inclusive
    __syncthreads();
    su[t] += vs; pv[t] += vp;
    __syncthreads();
  }
  sufug[b * 260 + t] = su[t];
  prevg[b * 260 + t] = (t > 0) ? pv[t - 1] : 0.f;
  if (t == 0) sufug[b * 260 + 256] = 0.f;
}

// ---------------- chunk sums: SU/SV[b][c][768] (f32) over 8 sorted rows each ----------
__global__ __launch_bounds__(192) void k_chunks(const unsigned short* __restrict__ xp,
                                                const int* __restrict__ sidx,
                                                const float* __restrict__ es1g,
                                                const float* __restrict__ es2g,
                                                float* __restrict__ SU, float* __restrict__ SV) {
  __shared__ int ridx[64];
  __shared__ float w1l[64], w2l[64];
  int b = blockIdx.y, cblk = blockIdx.x;   // 32 cblks x 8 chunks
  int t = threadIdx.x;
  if (t < 64) {
    int r = cblk * 64 + t;
    ridx[t] = sidx[b * S_ + r];
    w1l[t] = es1g[b * S_ + r];
    w2l[t] = es2g[b * S_ + r];
  }
  __syncthreads();
  int d0 = t * 4;
  const unsigned short* xb = xp + (size_t)b * S_ * D_;
  for (int q = 0; q < 8; ++q) {
    float a1[4] = {0.f, 0.f, 0.f, 0.f}, a2[4] = {0.f, 0.f, 0.f, 0.f};
#pragma unroll
    for (int r = 0; r < 8; ++r) {
      int j = q * 8 + r;
      ushort4v xv = *(const ushort4v*)(xb + (size_t)ridx[j] * D_ + d0);
      float w1 = w1l[j], w2 = w2l[j];
#pragma unroll
      for (int e = 0; e < 4; ++e) {
        float x = bf2f(xv[e]);
        a1[e] = fmaf(w1, x, a1[e]);
        a2[e] = fmaf(w2, x, a2[e]);
      }
    }
    int c = cblk * 8 + q;
    float4v o1, o2;
    o1[0] = a1[0]; o1[1] = a1[1]; o1[2] = a1[2]; o1[3] = a1[3];
    o2[0] = a2[0]; o2[1] = a2[1]; o2[2] = a2[2]; o2[3] = a2[3];
    *(float4v*)(SU + ((size_t)b * 256 + c) * D_ + d0) = o1;
    *(float4v*)(SV + ((size_t)b * 256 + c) * D_ + d0) = o2;
  }
}

// ---------------- scans over chunks: f32 in, bf16 out ----------------
__global__ __launch_bounds__(256) void k_scan(const float* __restrict__ SU,
                                              const float* __restrict__ SV,
                                              unsigned short* __restrict__ SUb,
                                              unsigned short* __restrict__ SVb) {
  __shared__ float sums[8][33];
  int b = blockIdx.y;
  int dl = threadIdx.x & 31, p = threadIdx.x >> 5;   // 32 d-cols x 8 c-parts
  int d = blockIdx.x * 32 + dl;
  const float* u = SU + (size_t)b * 256 * D_ + d;
  const float* v = SV + (size_t)b * 256 * D_ + d;
  unsigned short* ub = SUb + (size_t)b * 257 * D_ + d;
  unsigned short* vb = SVb + (size_t)b * 256 * D_ + d;
  int c0 = p * 32;
  float cu[32], cv[32];
  float su_ = 0.f, sv_ = 0.f;
#pragma unroll
  for (int q = 0; q < 32; ++q) {
    cu[q] = u[(size_t)(c0 + q) * D_];
    cv[q] = v[(size_t)(c0 + q) * D_];
    su_ += cu[q]; sv_ += cv[q];
  }
  sums[p][dl] = su_;
  __syncthreads();
  float offU = 0.f;
#pragma unroll
  for (int q = 0; q < 8; ++q) if (q > p) offU += sums[q][dl];
  __syncthreads();
  sums[p][dl] = sv_;
  __syncthreads();
  float offV = 0.f;
#pragma unroll
  for (int q = 0; q < 8; ++q) if (q < p) offV += sums[q][dl];
  float run = offU;
#pragma unroll
  for (int q = 31; q >= 0; --q) { run += cu[q]; ub[(size_t)(c0 + q) * D_] = f2bf(run); }
  float pr = offV;
#pragma unroll
  for (int q = 0; q < 32; ++q) { vb[(size_t)(c0 + q) * D_] = f2bf(pr); pr += cv[q]; }
  if (p == 0) ub[(size_t)256 * D_] = 0;
}

// ---------------- output (round-18 best): 8-i tiles, 2048 blocks, skeys stage ---------
__global__ __launch_bounds__(256) void k_out(const unsigned short* __restrict__ xp,
                                             const float* __restrict__ ad,
                                             const float* __restrict__ ssorted,
                                             const int* __restrict__ sidx,
                                             const float* __restrict__ es1g,
                                             const float* __restrict__ es2g,
                                             const float* __restrict__ sufug,
                                             const float* __restrict__ prevg,
                                             const float* __restrict__ msg,
                                             const unsigned short* __restrict__ SUb,
                                             const unsigned short* __restrict__ SVb,
                                             const float* __restrict__ b_gat,
                                             unsigned short* __restrict__ gout) {
  __shared__ float skeys[2048];
  __shared__ float G1[8], G2[8], WL[8][8];
  __shared__ int CI[8], RI[8][8];
  int bid = blockIdx.x;                 // 2048 blocks; bid&7 = batch (XCD affinity)
  int b = bid & 7, itile = bid >> 3;    // itile 0..255
  int i0 = itile * 8;
  int t = threadIdx.x;
#pragma unroll
  for (int k2 = 0; k2 < 2; ++k2) {
    int p = (t + k2 * 256) * 4;
    *(float4v*)(skeys + p) = *(const float4v*)(ssorted + b * S_ + p);
  }
  __syncthreads();
  if (t < 8) {
    int i = i0 + t;
    float di = ad[b * S_ + i];
    float thr = -di;
    int lo = 0, hi = 2048;
#pragma unroll
    for (int st = 0; st < 11; ++st) {
      int mid = (lo + hi) >> 1;
      if (skeys[mid] <= thr) lo = mid + 1; else hi = mid;
    }
    int c = lo >> 3; if (c > 255) c = 255;
    float t1 = di + msg[b];
    float mst = fmaxf(t1, 0.2f * t1);
    float g1 = __expf(t1 - mst), g2 = __expf(0.2f * t1 - mst);
    float den = g1 * sufug[b * 260 + c + 1] + g2 * prevg[b * 260 + c];
    float wr[8]; int rid[8];
#pragma unroll
    for (int r = 0; r < 8; ++r) {
      int row = c * 8 + r;
      bool neg = (skeys[row] <= thr);
      float wv = neg ? g2 * es2g[b * S_ + row] : g1 * es1g[b * S_ + row];
      den += wv;
      wr[r] = wv;
      rid[r] = sidx[b * S_ + row];
    }
    float inv = 1.f / den;
    G1[t] = g1 * inv; G2[t] = g2 * inv; CI[t] = c;
#pragma unroll
    for (int r = 0; r < 8; ++r) { WL[t][r] = wr[r] * inv; RI[t][r] = rid[r]; }
  }
  __syncthreads();
  int w = t >> 6, lane = t & 63;
  int dbase = lane * 4;
  float4v bgv[3];
#pragma unroll
  for (int q = 0; q < 3; ++q) bgv[q] = *(const float4v*)(b_gat + dbase + q * 256);
  const unsigned short* xb = xp + (size_t)b * S_ * D_;
  const unsigned short* SUbb = SUb + (size_t)b * 257 * D_;
  const unsigned short* SVbb = SVb + (size_t)b * 256 * D_;
#pragma unroll
  for (int rep = 0; rep < 2; ++rep) {
    int ii = w + rep * 4;
    int c = CI[ii];
    float g1 = G1[ii], g2 = G2[ii];
    size_t roff = ((size_t)(b * S_ + i0 + ii)) * D_;
    float4v o[3];
#pragma unroll
    for (int q = 0; q < 3; ++q) {
      int d = dbase + q * 256;
      ushort4v uu = *(const ushort4v*)(SUbb + (size_t)(c + 1) * D_ + d);
      ushort4v vv = *(const ushort4v*)(SVbb + (size_t)c * D_ + d);
#pragma unroll
      for (int e = 0; e < 4; ++e) o[q][e] = fmaf(g1, bf2f(uu[e]), g2 * bf2f(vv[e]));
    }
#pragma unroll
    for (int r = 0; r < 8; ++r) {
      float wv = WL[ii][r];
      const unsigned short* xr = xb + (size_t)RI[ii][r] * D_;
#pragma unroll
      for (int q = 0; q < 3; ++q) {
        int d = dbase + q * 256;
        ushort4v xv = *(const ushort4v*)(xr + d);
#pragma unroll
        for (int e = 0; e < 4; ++e) o[q][e] = fmaf(wv, bf2f(xv[e]), o[q][e]);
      }
    }
#pragma unroll
    for (int q = 0; q < 3; ++q) {
      int d = dbase + q * 256;
      ushort4v og;
      og[0] = f2bf(o[q][0] + bgv[q][0]); og[1] = f2bf(o[q][1] + bgv[q][1]);
      og[2] = f2bf(o[q][2] + bgv[q][2]); og[3] = f2bf(o[q][3] + bgv[q][3]);
      *(ushort4v*)(gout + roff + d) = og;
    }
  }
}

// ---------------- launch ----------------
extern "C" void kernel_launch(void* const* d_in, const int* in_sizes, int n_in,
                              void* d_out, int out_size, void* d_ws, size_t ws_size,
                              hipStream_t stream) {
  const float* hs   = (const float*)d_in[0];
  const float* to   = (const float*)d_in[1];
  const float* Wg   = (const float*)d_in[2];
  const float* asrc = (const float*)d_in[3];
  const float* adst = (const float*)d_in[4];
  const float* bg   = (const float*)d_in[5];
  const float* Wf   = (const float*)d_in[6];
  const float* bfu  = (const float*)d_in[7];
  float* out = (float*)d_out;

  char* ws = (char*)d_ws;
  size_t off = 0;
  auto alloc = [&](size_t bytes) {
    char* p = ws + off;
    off += (bytes + 255) & ~(size_t)255;
    return p;
  };
  unsigned short* hs_bf = (unsigned short*)alloc((size_t)BS_ * D_ * 2);  // reused as gout
  unsigned short* to_bf = (unsigned short*)alloc((size_t)BS_ * D_ * 2);
  unsigned short* xp    = (unsigned short*)alloc((size_t)BS_ * D_ * 2);
  unsigned short* WgT   = (unsigned short*)alloc((size_t)D_ * D_ * 2);
  unsigned short* WfT   = (unsigned short*)alloc((size_t)D_ * F_ * 2);
  float* as   = (float*)alloc((size_t)BS_ * 4);
  float* ad   = (float*)alloc((size_t)BS_ * 4);
  float* ssorted = (float*)alloc((size_t)BS_ * 4);
  int*   sidx    = (int*)alloc((size_t)BS_ * 4);
  float* es1g = (float*)alloc((size_t)BS_ * 4);
  float* es2g = (float*)alloc((size_t)BS_ * 4);
  float* sufug = (float*)alloc((size_t)B_ * 260 * 4);
  float* prevg = (float*)alloc((size_t)B_ * 260 * 4);
  float* msg   = (float*)alloc(256);
  float* SU = (float*)alloc((size_t)B_ * 256 * D_ * 4);               // chunk sums (f32)
  float* SV = (float*)alloc((size_t)B_ * 256 * D_ * 4);
  unsigned short* SUb = (unsigned short*)alloc((size_t)B_ * 257 * D_ * 2);  // scanned, bf16
  unsigned short* SVb = (unsigned short*)alloc((size_t)B_ * 256 * D_ * 2);
  unsigned short* gout = hs_bf;   // hs_bf dead after gemm1

  int n = BS_ * D_;
  k_cast8x2<<<n / 2048, 256, 0, stream>>>(hs, to, hs_bf, to_bf, n, as, ad);
  k_transpose2<<<dim3(24, 72), 256, 0, stream>>>(Wg, Wf, WgT, WfT);
  k_gemm1<<<768, 256, 0, stream>>>(hs_bf, WgT, D_, xp, asrc, adst, as, ad);
  k_rank<<<dim3(64, B_), 256, 0, stream>>>(as, ssorted, sidx, es1g, es2g, msg);
  k_pscan<<<B_, 256, 0, stream>>>(es1g, es2g, sufug, prevg);
  k_chunks<<<dim3(32, B_), 192, 0, stream>>>(xp, sidx, es1g, es2g, SU, SV);
  k_scan<<<dim3(24, B_), 256, 0, stream>>>(SU, SV, SUb, SVb);
  k_out<<<2048, 256, 0, stream>>>(xp, ad, ssorted, sidx, es1g, es2g, sufug, prevg, msg,
                                  SUb, SVb, bg, gout);
  k_gemm0<<<512, 256, 0, stream>>>(to_bf, gout, WfT, F_, D_, out, bfu);
}